// Round 4
// baseline (199.647 us; speedup 1.0000x reference)
//
#include <hip/hip_runtime.h>
#include <hip/hip_bf16.h>

#define KDIM 1024
#define NDIM 1024
#define NEXP 8
#define TTOK 8192
#define NT (KDIM / 32)

typedef __bf16 bf16x8 __attribute__((ext_vector_type(8)));
typedef __bf16 bf16x4 __attribute__((ext_vector_type(4)));
typedef float  f32x4  __attribute__((ext_vector_type(4)));

__device__ __forceinline__ void gl2lds16(const void* g, void* l) {
  __builtin_amdgcn_global_load_lds(
      (const __attribute__((address_space(1))) void*)g,
      (__attribute__((address_space(3))) void*)l, 16, 0, 0);
}

// swB slot(e,panel,kt,lane) = W[e][kt*32 + (lane>>4)*8 .. +8][panel*16 + (lane&15)]

// ---------------- prepass: W transpose fp32 -> bf16 swizzled (W-only; swA removed) ----------
__global__ __launch_bounds__(256) void prepass_w(
    const float* __restrict__ W, __bf16* __restrict__ swB)
{
  __shared__ __align__(16) __bf16 Lt[64 * 72];
  const int t = threadIdx.x;
  int bid = blockIdx.x;
  int e = bid >> 8, r = bid & 255;
  int k0 = (r >> 4) * 64, n0 = (r & 15) * 64;
  const float* Wp = W + (size_t)e * KDIM * NDIM;
  int rr0 = t >> 4, c4 = t & 15;
#pragma unroll
  for (int p = 0; p < 4; ++p) {
    int kk = rr0 + p * 16;
    float4 v = *(const float4*)(Wp + (size_t)(k0 + kk) * NDIM + n0 + c4 * 4);
    Lt[(c4 * 4 + 0) * 72 + kk] = (__bf16)v.x;
    Lt[(c4 * 4 + 1) * 72 + kk] = (__bf16)v.y;
    Lt[(c4 * 4 + 2) * 72 + kk] = (__bf16)v.z;
    Lt[(c4 * 4 + 3) * 72 + kk] = (__bf16)v.w;
  }
  __syncthreads();
#pragma unroll
  for (int q = 0; q < 2; ++q) {
    int slot = q * 256 + t;
    int lane = slot & 63, grp = slot >> 6;
    int np = grp & 3, kt2 = grp >> 2;
    int nl = np * 16 + (lane & 15);
    int kl = kt2 * 32 + ((lane >> 4) << 3);
    bf16x8 v = *(const bf16x8*)(Lt + nl * 72 + kl);
    int panel = (n0 >> 4) + np;
    int ktg = (k0 >> 5) + kt2;
    size_t sg = (((size_t)e * 64 + panel) * 32 + ktg) * 64 + lane;
    *(bf16x8*)(swB + sg * 8) = v;
  }
}

// ---------------- GEMM: A direct-from-x in registers, B via gl2lds, counted vmcnt ---------
// A fragments need NO transpose: aF[i] = x[row][k..k+8], 32B contiguous -> 2x dwordx4 fp32
// per lane + in-reg bf16 convert. No ds_write (no bank conflicts, no lgkmcnt coupling).
// x locality: XCD m-ownership (xcd=b&7 owns 9 contiguous m-tiles); all ~72 XCD blocks
// co-resident, reading the same kt-window -> each x line: 1 HBM fetch + 7 L2 hits.
//
// VMEM queue protocol (in-order retirement; A loads and B gl2lds share vmcnt):
//   steady iter-top queue: [B(kt):2][A(kt+1):8][B(kt+1):2] = 12
//     vmcnt(10) -> retires exactly B(kt); barrier -> LDS slice kt published
//     MFMA(kt); vmcnt(2) -> retires exactly A(kt+1); convert A(kt+1)->aF
//     issue A(kt+2) [8], stage B(kt+2) [2]  (A before B keeps the invariant)
//   prologue: A(0),B(0) -> vmcnt(2) retires A(0); convert; A(1),B(1) -> queue matches.
// WAR safety (3 buffers): stage B(kt+2) after barrier(kt); buf[(kt+2)%3]'s last readers
// ran compute(kt-1), which precedes barrier(kt) in every wave's program order.
__global__ __launch_bounds__(256, 3) void moe_gemm_lds(
    const float* __restrict__ x, const __bf16* __restrict__ swB,
    const int* __restrict__ gs, const float* __restrict__ bias,
    float* __restrict__ out)
{
  __shared__ __align__(16) __bf16 buf[3][4096];   // 3 x 8 KB (B only)

  const int b = blockIdx.x;
  const int xcd = b & 7, bi = b >> 3;
  int y = xcd * 9 + bi % 9;           // global m-tile index
  const int nt = bi / 9;

  int e = 0, tile0 = 0, lo = 0, hi = 0, found = 0, off = 0;
#pragma unroll
  for (int i = 0; i < NEXP; ++i) {
    int g = gs[i];
    int first = off >> 7;
    int cnt = (g > 0) ? (((off + g - 1) >> 7) - first + 1) : 0;
    if (!found) {
      if (y < cnt) {
        found = 1; e = i; tile0 = (first + y) << 7;
        lo = max(tile0, off); hi = min(tile0 + 128, off + g);
      } else y -= cnt;
    }
    off += g;
  }
  if (!found) return;                       // block-uniform: no barrier mismatch
  const int n0 = nt * 128;

  const int t = threadIdx.x, lane = t & 63, wv = t >> 6;
  const int wm = wv & 1, wn = wv >> 1, lm = lane & 15, lg = lane >> 4;

  // B staging: wave wv stages panels {wv, 4+wv} (panel stride = 32 kt * 512 = 16384 elems)
  const __bf16* gB0 = swB + (size_t)(e * 64 + (n0 >> 4) + wv) * 16384 + lane * 8;
  const __bf16* gB1 = swB + (size_t)(e * 64 + (n0 >> 4) + 4 + wv) * 16384 + lane * 8;

  auto stage_B = [&](int kt, int sb) {
    __bf16* l = &buf[sb][0];
    const int ko = kt * 512;
    gl2lds16(gB0 + ko, l + (size_t)(wv * 64) * 8);           // panel wv
    gl2lds16(gB1 + ko, l + (size_t)((4 + wv) * 64) * 8);     // panel 4+wv
  };

  // A direct loads: aF[i] <- x[tile0 + wm*64 + i*16 + lm][kt*32 + lg*8 .. +8]
  // per dwordx4 across the wave: 16 rows x full 128B lines (lg covers the line) -> all
  // fetched bytes consumed by the instruction pair.
  const float* xA = x + (size_t)(tile0 + wm * 64 + lm) * KDIM + lg * 8;
  float4 R[4][2];
  auto issue_x = [&](int kt) {
#pragma unroll
    for (int i = 0; i < 4; ++i) {
      const float* p = xA + (size_t)(i * 16) * KDIM + kt * 32;
      R[i][0] = *(const float4*)p;
      R[i][1] = *(const float4*)(p + 4);
    }
  };
  bf16x8 aF[4];
  auto convert_x = [&]() {
#pragma unroll
    for (int i = 0; i < 4; ++i) {
      bf16x8 v;
      v[0] = (__bf16)R[i][0].x; v[1] = (__bf16)R[i][0].y;
      v[2] = (__bf16)R[i][0].z; v[3] = (__bf16)R[i][0].w;
      v[4] = (__bf16)R[i][1].x; v[5] = (__bf16)R[i][1].y;
      v[6] = (__bf16)R[i][1].z; v[7] = (__bf16)R[i][1].w;
      aF[i] = v;
    }
  };

  f32x4 acc[4][4] = {};
  auto compute = [&](const __bf16* l) {
    bf16x8 bF[4];
#pragma unroll
    for (int j = 0; j < 4; ++j)
      bF[j] = *(const bf16x8*)(l + (size_t)((wn * 4 + j) * 64 + lane) * 8);
#pragma unroll
    for (int i = 0; i < 4; ++i)
#pragma unroll
      for (int j = 0; j < 4; ++j)
        acc[i][j] = __builtin_amdgcn_mfma_f32_16x16x32_bf16(aF[i], bF[j], acc[i][j], 0, 0, 0);
  };

  // prologue (queue after each step shown oldest->newest):
  issue_x(0);                                         // [A0:8]
  stage_B(0, 0);                                      // [A0:8][B0:2]
  asm volatile("s_waitcnt vmcnt(2)" ::: "memory");    // retires A0 exactly
  convert_x();                                        // aF = A(0)
  issue_x(1);                                         // [B0:2][A1:8]
  stage_B(1, 1);                                      // [B0:2][A1:8][B1:2] = steady invariant

#pragma unroll 1
  for (int kt = 0; kt < NT - 1; ++kt) {
    asm volatile("s_waitcnt vmcnt(10)" ::: "memory"); // retires B(kt): slice kt in LDS
    asm volatile("s_barrier" ::: "memory");
    compute(&buf[kt % 3][0]);
    asm volatile("s_waitcnt vmcnt(2)" ::: "memory");  // retires A(kt+1): regs ready
    convert_x();                                      // aF = A(kt+1)
    if (kt + 2 < NT) {
      issue_x(kt + 2);                                // A before B: keeps queue invariant
      stage_B(kt + 2, (kt + 2) % 3);
    }
  }
  asm volatile("s_waitcnt vmcnt(0)" ::: "memory");    // last B slice: nothing left in flight
  asm volatile("s_barrier" ::: "memory");
  compute(&buf[(NT - 1) % 3][0]);

  float bj[4];
#pragma unroll
  for (int j = 0; j < 4; ++j) bj[j] = bias[e * NDIM + n0 + wn * 64 + j * 16 + lm];
#pragma unroll
  for (int i = 0; i < 4; ++i)
#pragma unroll
    for (int r = 0; r < 4; ++r) {
      int rabs = tile0 + wm * 64 + i * 16 + lg * 4 + r;   // C/D: row = quad*4 + reg
      if (rabs >= lo && rabs < hi) {
#pragma unroll
        for (int j = 0; j < 4; ++j)
          out[(size_t)rabs * NDIM + n0 + wn * 64 + j * 16 + lm] = acc[i][j][r] + bj[j];
      }
    }
}

// ---------------- fallback (fp32 in-loop conversion) for small ws ----------------
#define LDA 40
__global__ __launch_bounds__(256) void moe_gemm_kernel(
    const float* __restrict__ x, const int* __restrict__ gs,
    const float* __restrict__ W, const float* __restrict__ bias,
    float* __restrict__ out)
{
  __shared__ __bf16 Al[128 * LDA];
  __shared__ __bf16 Bl[128 * LDA];
  const int e = blockIdx.z, mt = blockIdx.y, nt = blockIdx.x;
  int off = 0;
#pragma unroll
  for (int i = 0; i < NEXP; ++i) { int g = gs[i]; if (i < e) off += g; }
  const int ge = gs[e];
  const int m0 = mt * 128;
  if (m0 >= ge) return;
  const int rows = min(128, ge - m0);
  const int row0 = off + m0;
  const int n0 = nt * 128;
  const int t = threadIdx.x, lane = t & 63, wv = t >> 6;
  const int wm = wv & 1, wn = wv >> 1, lm = lane & 15, lg = lane >> 4;
  const int am = t >> 3, kq = t & 7, nb = t & 127, kh = t >> 7;
  float4 aReg[4]; float bReg[16];
  const float* Wp = W + (size_t)e * KDIM * NDIM + n0 + nb;
  auto load_tile = [&](int kt) {
#pragma unroll
    for (int p = 0; p < 4; ++p) {
      int r = am + 32 * p;
      if (r < rows) aReg[p] = *(const float4*)(x + (size_t)(row0 + r) * KDIM + kt * 32 + kq * 4);
      else aReg[p] = make_float4(0.f, 0.f, 0.f, 0.f);
    }
    const float* wp = Wp + (size_t)(kt * 32 + kh * 16) * NDIM;
#pragma unroll
    for (int j = 0; j < 16; ++j) bReg[j] = wp[(size_t)j * NDIM];
  };
  auto store_tile = [&]() {
#pragma unroll
    for (int p = 0; p < 4; ++p) {
      bf16x4 v;
      v[0] = (__bf16)aReg[p].x; v[1] = (__bf16)aReg[p].y;
      v[2] = (__bf16)aReg[p].z; v[3] = (__bf16)aReg[p].w;
      *(bf16x4*)(Al + (am + 32 * p) * LDA + kq * 4) = v;
    }
    bf16x8 b0, b1;
#pragma unroll
    for (int j = 0; j < 8; ++j) { b0[j] = (__bf16)bReg[j]; b1[j] = (__bf16)bReg[8 + j]; }
    *(bf16x8*)(Bl + nb * LDA + kh * 16) = b0;
    *(bf16x8*)(Bl + nb * LDA + kh * 16 + 8) = b1;
  };
  f32x4 acc[4][4] = {};
  load_tile(0);
#pragma unroll 1
  for (int kt = 0; kt < KDIM / 32; ++kt) {
    __syncthreads();
    store_tile();
    __syncthreads();
    if (kt + 1 < KDIM / 32) load_tile(kt + 1);
    bf16x8 af[4], bfr[4];
#pragma unroll
    for (int i = 0; i < 4; ++i)
      af[i] = *(const bf16x8*)(Al + (wm * 64 + i * 16 + lm) * LDA + lg * 8);
#pragma unroll
    for (int j = 0; j < 4; ++j)
      bfr[j] = *(const bf16x8*)(Bl + (wn * 64 + j * 16 + lm) * LDA + lg * 8);
#pragma unroll
    for (int i = 0; i < 4; ++i)
#pragma unroll
      for (int j = 0; j < 4; ++j)
        acc[i][j] = __builtin_amdgcn_mfma_f32_16x16x32_bf16(af[i], bfr[j], acc[i][j], 0, 0, 0);
  }
  float bj[4];
#pragma unroll
  for (int j = 0; j < 4; ++j) bj[j] = bias[e * NDIM + n0 + wn * 64 + j * 16 + lm];
#pragma unroll
  for (int i = 0; i < 4; ++i)
#pragma unroll
    for (int r = 0; r < 4; ++r) {
      int rr = wm * 64 + i * 16 + lg * 4 + r;
      if (rr < rows) {
#pragma unroll
        for (int j = 0; j < 4; ++j)
          out[(size_t)(row0 + rr) * NDIM + n0 + wn * 64 + j * 16 + lm] = acc[i][j][r] + bj[j];
      }
    }
}

extern "C" void kernel_launch(void* const* d_in, const int* in_sizes, int n_in,
                              void* d_out, int out_size, void* d_ws, size_t ws_size,
                              hipStream_t stream) {
  const float* x    = (const float*)d_in[0];
  const int*   gs   = (const int*)d_in[1];
  const float* W    = (const float*)d_in[2];
  const float* bias = (const float*)d_in[3];
  float*       out  = (float*)d_out;

  const size_t swB_bytes = (size_t)NEXP * KDIM * NDIM * 2;
  if (ws_size >= swB_bytes) {
    __bf16* swB = (__bf16*)d_ws;
    prepass_w<<<dim3(2048), 256, 0, stream>>>(W, swB);
    // 1D grid, XCD-contiguous m-ranges: xcd=b&7 owns m-tiles [9*xcd, 9*xcd+9) x all n.
    moe_gemm_lds<<<dim3(576), 256, 0, stream>>>(x, swB, gs, bias, out);
  } else {
    moe_gemm_kernel<<<dim3(NDIM / 128, TTOK / 128, NEXP), 256, 0, stream>>>(x, gs, W, bias, out);
  }
}